// Round 8
// baseline (535.128 us; speedup 1.0000x reference)
//
#include <hip/hip_runtime.h>

typedef __bf16 bf16x8 __attribute__((ext_vector_type(8)));
typedef __bf16 bf16x4 __attribute__((ext_vector_type(4)));
typedef float  f32x4  __attribute__((ext_vector_type(4)));

#define BATCH 4
#define SEQ 2048
#define DMODEL 1024
#define M_ROWS (BATCH * SEQ)      // 8192
#define NCHUNK 32
#define CLEN 64

// ---------------------------------------------------------------
// async 16B global -> LDS, gfx950
// ---------------------------------------------------------------
__device__ __forceinline__ void gload_lds16(const __bf16* g, __bf16* l) {
    __builtin_amdgcn_global_load_lds(
        (const __attribute__((address_space(1))) void*)g,
        (__attribute__((address_space(3))) void*)l, 16, 0, 0);
}

// ---------------------------------------------------------------
// Conversions + Wx transpose, one dispatch.
//  seg A: x -> hi/lo split (4 elems/thread)
//  seg B: in_proj_w -> hi/lo split
//  seg C: out_proj_w -> bf16
//  seg D: x_proj_w (33,1024) -> WxT (1024,36) f32, row-padded for float4
// ---------------------------------------------------------------
#define GX (M_ROWS * DMODEL / 4)          // 2097152
#define GW (2 * DMODEL * DMODEL / 4)      //  524288
#define GO (DMODEL * DMODEL / 4)          //  262144
#define GT (33 * DMODEL)                  //   33792
#define NTOT (GX + GW + GO + GT)          // 2917376 = 11396*256

__global__ __launch_bounds__(256) void cvt_all(
    const float* __restrict__ x, const float* __restrict__ wi,
    const float* __restrict__ wo, const float* __restrict__ wx,
    __bf16* __restrict__ x_hi, __bf16* __restrict__ x_lo,
    __bf16* __restrict__ wi_hi, __bf16* __restrict__ wi_lo,
    __bf16* __restrict__ wo_b, float* __restrict__ wxT)
{
    const int g = blockIdx.x * 256 + threadIdx.x;
    if (g < GX + GW) {
        const float* src = (g < GX) ? x : wi;
        __bf16* dh = (g < GX) ? x_hi : wi_hi;
        __bf16* dl = (g < GX) ? x_lo : wi_lo;
        const int i = (g < GX) ? g : g - GX;
        const f32x4 v = *(const f32x4*)(src + (size_t)i * 4);
        bf16x4 h, l;
#pragma unroll
        for (int j = 0; j < 4; ++j) {
            h[j] = (__bf16)v[j];
            l[j] = (__bf16)(v[j] - (float)h[j]);
        }
        *(bf16x4*)(dh + (size_t)i * 4) = h;
        *(bf16x4*)(dl + (size_t)i * 4) = l;
    } else if (g < GX + GW + GO) {
        const int i = g - GX - GW;
        const f32x4 v = *(const f32x4*)(wo + (size_t)i * 4);
        bf16x4 o;
#pragma unroll
        for (int j = 0; j < 4; ++j) o[j] = (__bf16)v[j];
        *(bf16x4*)(wo_b + (size_t)i * 4) = o;
    } else {
        const int i = g - GX - GW - GO;    // 0 .. 33*1024-1
        const int d = i / 33;
        const int e = i - d * 33;
        wxT[d * 36 + e] = wx[e * DMODEL + d];
    }
}

// ---------------------------------------------------------------
// Tiled GEMM: C[m][n] = sum_k A[m][k]*W[n][k].
// 128x128 tile, BK=32, 4 waves, each a 64x64 quadrant (4x4 accs).
// A: direct global->VGPR, software-pipelined one k-iter ahead.
// B: LDS ping-pong (2 x 8KB per matrix), staged via global_load_lds,
//    fragment-linear. ONE barrier per k-iter.
// SPLIT: f32-accurate via Al*Bh + Ah*Bl + Ah*Bh.
// ---------------------------------------------------------------
template <bool SPLIT>
__global__ __launch_bounds__(256) void gemm_tile(
    const __bf16* __restrict__ Ah, const __bf16* __restrict__ Al,
    const __bf16* __restrict__ Bh, const __bf16* __restrict__ Bl,
    float* __restrict__ C, int K, int N)
{
    constexpr int BUF = 128 * 32;                 // 4096 elems = 8 KB
    constexpr int PP  = (SPLIT ? 2 : 1) * BUF;    // ping-pong stride
    constexpr int NST = SPLIT ? 4 : 2;            // stage ops per wave
    __shared__ alignas(16) __bf16 smem[2 * PP];

    const int lane = threadIdx.x & 63;
    const int wave = threadIdx.x >> 6;
    const int bm = blockIdx.y * 128;
    const int bn = blockIdx.x * 128;
    const int sub_r = lane & 15;
    const int kq = (lane >> 4) * 8;

    // A direct-load base (per-wave 64-row quadrant)
    const size_t aoff = (size_t)(bm + (wave & 1) * 64 + sub_r) * K + kq;

    // B staging assignment (wave-static)
    const __bf16* gB[NST];
    int sB[NST];
#pragma unroll
    for (int j = 0; j < NST; ++j) {
        const int i = NST * wave + j;
        const __bf16* mat;
        int s, boff;
        if (SPLIT) { mat = (i < 8) ? Bh : Bl; s = i & 7; boff = (i >> 3) * BUF; }
        else       { mat = Bh;                s = i;     boff = 0; }
        gB[j] = mat + (size_t)(bn + s * 16 + sub_r) * K + kq;
        sB[j] = boff + s * 512 + lane * 8;
    }

    f32x4 acc[4][4] = {};
    const int nq = (wave >> 1) * 4;

    // ---- prologue: stage B(0) into buf0, load A(0) ----
#pragma unroll
    for (int j = 0; j < NST; ++j) gload_lds16(gB[j], smem + sB[j]);
    bf16x8 ah[4], al[4], ahn[4], aln[4];
#pragma unroll
    for (int mi = 0; mi < 4; ++mi) {
        ah[mi] = *(const bf16x8*)(Ah + aoff + (size_t)mi * 16 * K);
        if (SPLIT) al[mi] = *(const bf16x8*)(Al + aoff + (size_t)mi * 16 * K);
    }
    __syncthreads();

    int p = 0;
    for (int k0 = 0; k0 < K; k0 += 32) {
        const int kn = k0 + 32;
        if (kn < K) {
#pragma unroll
            for (int j = 0; j < NST; ++j)
                gload_lds16(gB[j] + kn, smem + (p ^ 1) * PP + sB[j]);
#pragma unroll
            for (int mi = 0; mi < 4; ++mi) {
                ahn[mi] = *(const bf16x8*)(Ah + aoff + (size_t)mi * 16 * K + kn);
                if (SPLIT) aln[mi] = *(const bf16x8*)(Al + aoff + (size_t)mi * 16 * K + kn);
            }
        }
        const __bf16* base = smem + p * PP;
        bf16x8 bh[4], bl[4];
#pragma unroll
        for (int ni = 0; ni < 4; ++ni) {
            bh[ni] = *(const bf16x8*)(base + (nq + ni) * 512 + lane * 8);
            if (SPLIT) bl[ni] = *(const bf16x8*)(base + BUF + (nq + ni) * 512 + lane * 8);
        }
#pragma unroll
        for (int mi = 0; mi < 4; ++mi) {
#pragma unroll
            for (int ni = 0; ni < 4; ++ni) {
                if (SPLIT) {
                    acc[mi][ni] = __builtin_amdgcn_mfma_f32_16x16x32_bf16(al[mi], bh[ni], acc[mi][ni], 0, 0, 0);
                    acc[mi][ni] = __builtin_amdgcn_mfma_f32_16x16x32_bf16(ah[mi], bl[ni], acc[mi][ni], 0, 0, 0);
                }
                acc[mi][ni] = __builtin_amdgcn_mfma_f32_16x16x32_bf16(ah[mi], bh[ni], acc[mi][ni], 0, 0, 0);
            }
        }
#pragma unroll
        for (int mi = 0; mi < 4; ++mi) {
            ah[mi] = ahn[mi];
            if (SPLIT) al[mi] = aln[mi];
        }
        p ^= 1;
        __syncthreads();
    }

    // ---- epilogue: D layout row=(l>>4)*4+r, col=l&15 ----
    const int r_off = (lane >> 4) * 4;
    const int cc = lane & 15;
#pragma unroll
    for (int mi = 0; mi < 4; ++mi) {
        const int row0 = bm + (wave & 1) * 64 + mi * 16 + r_off;
#pragma unroll
        for (int ni = 0; ni < 4; ++ni) {
            const int col = bn + (wave >> 1) * 64 + ni * 16 + cc;
#pragma unroll
            for (int r = 0; r < 4; ++r)
                C[(size_t)(row0 + r) * N + col] = acc[mi][ni][r];
        }
    }
}

// ---------------------------------------------------------------
// Fused conv(4)+bias+SiLU -> x_proj(+softplus), WxT (1024,36) f32.
// ---------------------------------------------------------------
__global__ __launch_bounds__(256) void conv_xproj_kernel(
    const float* __restrict__ xz,
    const float* __restrict__ conv_w,
    const float* __restrict__ conv_b,
    const float* __restrict__ WxT,    // (1024, 36)
    float* __restrict__ x_conv,
    float* __restrict__ P)            // (M,33)
{
    const int wave = threadIdx.x >> 6;
    const int lane = threadIdx.x & 63;
    const int m = blockIdx.x * 4 + wave;
    const int l = m & (SEQ - 1);

    float acc[33];
#pragma unroll
    for (int e = 0; e < 33; ++e) acc[e] = 0.f;

    for (int d = lane; d < DMODEL; d += 64) {
        float cacc = conv_b[d];
#pragma unroll
        for (int k = 0; k < 4; ++k) {
            const int ll = l + k - 3;
            if (ll >= 0)
                cacc += xz[(size_t)(m + k - 3) * 2048 + d] * conv_w[d * 4 + k];
        }
        const float xc = cacc / (1.f + __expf(-cacc));   // SiLU
        x_conv[(size_t)m * DMODEL + d] = xc;
        const f32x4* wr = (const f32x4*)(WxT + (size_t)d * 36);
#pragma unroll
        for (int q = 0; q < 8; ++q) {
            const f32x4 w = wr[q];
#pragma unroll
            for (int j = 0; j < 4; ++j) acc[q * 4 + j] += xc * w[j];
        }
        acc[32] += xc * WxT[(size_t)d * 36 + 32];
    }
#pragma unroll
    for (int e = 0; e < 33; ++e) {
        float v = acc[e];
#pragma unroll
        for (int off = 32; off; off >>= 1) v += __shfl_xor(v, off, 64);
        acc[e] = v;
    }
    if (lane == 0) {
        float* out = P + (size_t)m * 33;
        for (int e = 0; e < 32; ++e) out[e] = acc[e];
        const float x = acc[32];
        out[32] = (x > 20.f) ? x : log1pf(expf(x));      // softplus
    }
}

// ---------------------------------------------------------------
// Chunked parallel scan (3 phases).
// ---------------------------------------------------------------
__global__ __launch_bounds__(256) void scan_phase1(
    const float* __restrict__ P,
    const float* __restrict__ xc,
    const float* __restrict__ A_log,
    __bf16* __restrict__ hbuf,
    float* __restrict__ S)
{
    const int d = blockIdx.x * 256 + threadIdx.x;
    const int c = blockIdx.y;
    const int b = blockIdx.z;
    const int l0 = c * CLEN;

    __shared__ float buf[CLEN * 33];
    const float* src = P + (size_t)(b * SEQ + l0) * 33;
    for (int idx = threadIdx.x; idx < CLEN * 33; idx += 256)
        buf[idx] = src[idx];
    __syncthreads();

    if (threadIdx.x == 0 && blockIdx.x == 0) {
        float s = 0.f;
        for (int j = 0; j < CLEN; ++j) s += buf[j * 33 + 32];
        S[b * NCHUNK + c] = s;
    }

    float a[16];
#pragma unroll
    for (int n = 0; n < 16; ++n) a[n] = -__expf(A_log[d * 16 + n]);
    float h[16];
#pragma unroll
    for (int n = 0; n < 16; ++n) h[n] = 0.f;

    for (int j = 0; j < CLEN; ++j) {
        const int m = b * SEQ + l0 + j;
        const float xv = xc[(size_t)m * 1024 + d];
        const float* pp = &buf[j * 33];
        const float delta = pp[32];
        const float dx = delta * xv;
#pragma unroll
        for (int n = 0; n < 16; ++n)
            h[n] = __expf(delta * a[n]) * h[n] + dx * pp[n];
    }

    __bf16* hp = hbuf + ((size_t)(b * NCHUNK + c) * 1024 + d) * 16;
#pragma unroll
    for (int n = 0; n < 16; ++n) hp[n] = (__bf16)h[n];
}

__global__ __launch_bounds__(256) void scan_phase2(
    const float* __restrict__ A_log,
    const float* __restrict__ S,
    __bf16* __restrict__ hbuf)
{
    const int n = threadIdx.x & 15;
    const int d = blockIdx.x * 16 + (threadIdx.x >> 4);
    const int b = blockIdx.y;
    const float a = -__expf(A_log[d * 16 + n]);
    float h = 0.f;
    for (int c = 0; c < NCHUNK; ++c) {
        const size_t off = ((size_t)(b * NCHUNK + c) * 1024 + d) * 16 + n;
        const float he = (float)hbuf[off];
        hbuf[off] = (__bf16)h;
        h = __expf(a * S[b * NCHUNK + c]) * h + he;
    }
}

__global__ __launch_bounds__(256) void scan_phase3(
    const float* __restrict__ P,
    const float* __restrict__ xc,
    const float* __restrict__ xz,
    const float* __restrict__ A_log,
    const float* __restrict__ Dp,
    const __bf16* __restrict__ hbuf,
    __bf16* __restrict__ Y)
{
    const int d = blockIdx.x * 256 + threadIdx.x;
    const int c = blockIdx.y;
    const int b = blockIdx.z;
    const int l0 = c * CLEN;

    __shared__ float buf[CLEN * 33];
    const float* src = P + (size_t)(b * SEQ + l0) * 33;
    for (int idx = threadIdx.x; idx < CLEN * 33; idx += 256)
        buf[idx] = src[idx];
    __syncthreads();

    float a[16];
#pragma unroll
    for (int n = 0; n < 16; ++n) a[n] = -__expf(A_log[d * 16 + n]);
    const float Dv = Dp[d];

    const __bf16* hp = hbuf + ((size_t)(b * NCHUNK + c) * 1024 + d) * 16;
    float h[16];
#pragma unroll
    for (int n = 0; n < 16; ++n) h[n] = (float)hp[n];

    for (int j = 0; j < CLEN; ++j) {
        const int m = b * SEQ + l0 + j;
        const float xv = xc[(size_t)m * 1024 + d];
        const float zv = xz[(size_t)m * 2048 + 1024 + d];
        const float* pp = &buf[j * 33];
        const float delta = pp[32];
        const float dx = delta * xv;
        float y = 0.f;
#pragma unroll
        for (int n = 0; n < 16; ++n) {
            h[n] = __expf(delta * a[n]) * h[n] + dx * pp[n];
            y += h[n] * pp[16 + n];
        }
        y += Dv * xv;
        const float sz = zv / (1.f + __expf(-zv));
        Y[(size_t)m * 1024 + d] = (__bf16)(y * sz);
    }
}

// ---------------------------------------------------------------
extern "C" void kernel_launch(void* const* d_in, const int* in_sizes, int n_in,
                              void* d_out, int out_size, void* d_ws, size_t ws_size,
                              hipStream_t stream) {
    const float* x          = (const float*)d_in[0];
    const float* in_proj_w  = (const float*)d_in[1];
    const float* conv_w     = (const float*)d_in[2];
    const float* conv_b     = (const float*)d_in[3];
    const float* x_proj_w   = (const float*)d_in[4];
    const float* A_log      = (const float*)d_in[5];
    const float* D_param    = (const float*)d_in[6];
    const float* out_proj_w = (const float*)d_in[7];
    float* out = (float*)d_out;

    char* ws = (char*)d_ws;
    // Lifetimes:
    //  t0 cvt_all   writes x_hi,x_lo,wi_hi,wi_lo,wo,wxT
    //  t1 gemm_split reads x_*,wi_* -> writes xz
    //  t2 conv_xproj reads xz,wxT -> writes xconv,params (over x_hi/wi_hi; dead)
    //  t3 scan      reads params,xconv,xz -> writes hbuf,y (y over wxT; wxT dead)
    //  t4 out_proj  reads y,wo -> writes out
    float*  xz     = (float*)(ws);                 // [0, 64M)
    __bf16* x_hi   = (__bf16*)(ws + 67108864);     // [64M, 80M)
    __bf16* x_lo   = (__bf16*)(ws + 83886080);     // [80M, 96M)
    __bf16* wi_hi  = (__bf16*)(ws + 100663296);    // [96M, 100M)
    __bf16* wi_lo  = (__bf16*)(ws + 104857600);    // [100M, 104M)
    float*  xconv  = (float*)(ws + 67108864);      // t2+: over x_hi/x_lo
    float*  params = (float*)(ws + 100663296);     // t2+: over wi_hi head
    __bf16* hbuf   = (__bf16*)(ws + 101744640);    // t3: 4 MiB
    float*  Sbuf   = (float*)(ws + 105938944);     // t3: 512 B
    __bf16* y      = (__bf16*)(ws + 109051904);    // t3+: 16 MiB
    float*  wxT    = (float*)(ws + 109051904);     // t0-t2: head of y region (dead until t3)
    __bf16* wo     = (__bf16*)(ws + 125829120);    // 2 MiB

    // 0) conversions + Wx transpose
    cvt_all<<<NTOT / 256, 256, 0, stream>>>(
        x, in_proj_w, out_proj_w, x_proj_w,
        x_hi, x_lo, wi_hi, wi_lo, wo, wxT);

    // 1) in_proj (M=8192,N=2048,K=1024), f32-accurate split
    gemm_tile<true><<<dim3(2048 / 128, M_ROWS / 128), 256, 0, stream>>>(
        x_hi, x_lo, wi_hi, wi_lo, xz, DMODEL, 2048);

    // 2) fused conv+SiLU+x_proj(+softplus)
    conv_xproj_kernel<<<M_ROWS / 4, 256, 0, stream>>>(
        xz, conv_w, conv_b, wxT, xconv, params);

    // 3) chunked parallel scan
    scan_phase1<<<dim3(DMODEL / 256, NCHUNK, BATCH), 256, 0, stream>>>(
        params, xconv, A_log, hbuf, Sbuf);
    scan_phase2<<<dim3(DMODEL / 16, BATCH), 256, 0, stream>>>(
        A_log, Sbuf, hbuf);
    scan_phase3<<<dim3(DMODEL / 256, NCHUNK, BATCH), 256, 0, stream>>>(
        params, xconv, xz, A_log, D_param, hbuf, y);

    // 4) out_proj (M=8192,N=1024,K=1024), plain bf16
    gemm_tile<false><<<dim3(1024 / 128, M_ROWS / 128), 256, 0, stream>>>(
        y, nullptr, wo, nullptr, out, DMODEL, 1024);
}

// Round 9
// 452.547 us; speedup vs baseline: 1.1825x; 1.1825x over previous
//
#include <hip/hip_runtime.h>

typedef __bf16 bf16x8 __attribute__((ext_vector_type(8)));
typedef __bf16 bf16x4 __attribute__((ext_vector_type(4)));
typedef float  f32x4  __attribute__((ext_vector_type(4)));

#define BATCH 4
#define SEQ 2048
#define DMODEL 1024
#define M_ROWS (BATCH * SEQ)      // 8192
#define NCHUNK 32
#define CLEN 64

// ---------------------------------------------------------------
// async 16B global -> LDS, gfx950
// ---------------------------------------------------------------
__device__ __forceinline__ void gload_lds16(const __bf16* g, __bf16* l) {
    __builtin_amdgcn_global_load_lds(
        (const __attribute__((address_space(1))) void*)g,
        (__attribute__((address_space(3))) void*)l, 16, 0, 0);
}

// ---------------------------------------------------------------
// Conversions + Wx transpose, one dispatch.
//  seg A: x -> bf16 (hi only; in_proj uses exact-W x trunc-A scheme)
//  seg B: in_proj_w -> hi/lo split
//  seg C: out_proj_w -> bf16
//  seg D: x_proj_w (33,1024) -> WxT (1024,36) f32
// ---------------------------------------------------------------
#define GX (M_ROWS * DMODEL / 4)          // 2097152
#define GW (2 * DMODEL * DMODEL / 4)      //  524288
#define GO (DMODEL * DMODEL / 4)          //  262144
#define GT (33 * DMODEL)                  //   33792
#define NTOT (GX + GW + GO + GT)

__global__ __launch_bounds__(256) void cvt_all(
    const float* __restrict__ x, const float* __restrict__ wi,
    const float* __restrict__ wo, const float* __restrict__ wx,
    __bf16* __restrict__ x_hi,
    __bf16* __restrict__ wi_hi, __bf16* __restrict__ wi_lo,
    __bf16* __restrict__ wo_b, float* __restrict__ wxT)
{
    const int g = blockIdx.x * 256 + threadIdx.x;
    if (g < GX) {
        const f32x4 v = *(const f32x4*)(x + (size_t)g * 4);
        bf16x4 h;
#pragma unroll
        for (int j = 0; j < 4; ++j) h[j] = (__bf16)v[j];
        *(bf16x4*)(x_hi + (size_t)g * 4) = h;
    } else if (g < GX + GW) {
        const int i = g - GX;
        const f32x4 v = *(const f32x4*)(wi + (size_t)i * 4);
        bf16x4 h, l;
#pragma unroll
        for (int j = 0; j < 4; ++j) {
            h[j] = (__bf16)v[j];
            l[j] = (__bf16)(v[j] - (float)h[j]);
        }
        *(bf16x4*)(wi_hi + (size_t)i * 4) = h;
        *(bf16x4*)(wi_lo + (size_t)i * 4) = l;
    } else if (g < GX + GW + GO) {
        const int i = g - GX - GW;
        const f32x4 v = *(const f32x4*)(wo + (size_t)i * 4);
        bf16x4 o;
#pragma unroll
        for (int j = 0; j < 4; ++j) o[j] = (__bf16)v[j];
        *(bf16x4*)(wo_b + (size_t)i * 4) = o;
    } else {
        const int i = g - GX - GW - GO;    // 0 .. 33*1024-1
        const int d = i / 33;
        const int e = i - d * 33;
        wxT[d * 36 + e] = wx[e * DMODEL + d];
    }
}

// ---------------------------------------------------------------
// Tiled GEMM (round-6 two-barrier structure): C[m][n] = sum_k A[m][k]*W[n][k].
// 128x128 tile, BK=32, 4 waves, each a 64x64 quadrant (4x4 accs).
// LDS in MFMA-fragment-linear order (sub-tile = 16 rows x 32 k = 512
// elems; lane l = row 16s+(l&15), k-off (l>>4)*8, at s*512+l*8),
// staged via global_load_lds(16B), wave-static & unrolled.
// BSPLIT: C = Ah*(Bh+Bl) -- exact weights, bf16-truncated activations
//         (2 MFMA per sub-product; error ~4e-4 RMS on xz, see notes).
// ---------------------------------------------------------------
template <bool BSPLIT>
__global__ __launch_bounds__(256) void gemm_tile(
    const __bf16* __restrict__ A, const __bf16* __restrict__ Bh,
    const __bf16* __restrict__ Bl,
    float* __restrict__ C, int K, int N)
{
    constexpr int BUF = 128 * 32;                 // 4096 elems = 8 KB
    constexpr int NMAT = BSPLIT ? 3 : 2;          // A,Bh[,Bl]
    constexpr int NST = BSPLIT ? 6 : 4;           // stage ops per wave
    __shared__ alignas(16) __bf16 smem[NMAT * BUF];

    const int lane = threadIdx.x & 63;
    const int wave = threadIdx.x >> 6;
    const int bm = blockIdx.y * 128;
    const int bn = blockIdx.x * 128;
    const int sub_r = lane & 15;
    const int kq = (lane >> 4) * 8;

    __bf16* sA  = smem;
    __bf16* sBh = smem + BUF;
    __bf16* sBl = smem + 2 * BUF;                 // BSPLIT only

    // wave-static staging assignment: i = NST*wave + j,
    // buf = i>>3 (0=A,1=Bh,2=Bl), s = i&7
    const __bf16* gS[NST];
    int sS[NST];
#pragma unroll
    for (int j = 0; j < NST; ++j) {
        const int i = NST * wave + j;
        const int buf = i >> 3;
        const int s = i & 7;
        const __bf16* mat = (buf == 0) ? A : (buf == 1) ? Bh : Bl;
        const int rbase = (buf == 0) ? bm : bn;
        gS[j] = mat + (size_t)(rbase + s * 16 + sub_r) * K + kq;
        sS[j] = buf * BUF + s * 512 + lane * 8;
    }

    f32x4 acc[4][4] = {};
    const int mq = (wave & 1) * 4;
    const int nq = (wave >> 1) * 4;

    for (int k0 = 0; k0 < K; k0 += 32) {
        // ---- stage ----
#pragma unroll
        for (int j = 0; j < NST; ++j)
            gload_lds16(gS[j] + k0, smem + sS[j]);
        __syncthreads();

        // ---- compute ----
        bf16x8 bh[4], bl[4];
#pragma unroll
        for (int ni = 0; ni < 4; ++ni) {
            bh[ni] = *(const bf16x8*)(sBh + (nq + ni) * 512 + lane * 8);
            if (BSPLIT) bl[ni] = *(const bf16x8*)(sBl + (nq + ni) * 512 + lane * 8);
        }
#pragma unroll
        for (int mi = 0; mi < 4; ++mi) {
            bf16x8 av = *(const bf16x8*)(sA + (mq + mi) * 512 + lane * 8);
#pragma unroll
            for (int ni = 0; ni < 4; ++ni) {
                if (BSPLIT)
                    acc[mi][ni] = __builtin_amdgcn_mfma_f32_16x16x32_bf16(av, bl[ni], acc[mi][ni], 0, 0, 0);
                acc[mi][ni] = __builtin_amdgcn_mfma_f32_16x16x32_bf16(av, bh[ni], acc[mi][ni], 0, 0, 0);
            }
        }
        __syncthreads();
    }

    // ---- epilogue: D layout row=(l>>4)*4+r, col=l&15 ----
    const int r_off = (lane >> 4) * 4;
    const int cc = lane & 15;
#pragma unroll
    for (int mi = 0; mi < 4; ++mi) {
        const int row0 = bm + (wave & 1) * 64 + mi * 16 + r_off;
#pragma unroll
        for (int ni = 0; ni < 4; ++ni) {
            const int col = bn + (wave >> 1) * 64 + ni * 16 + cc;
#pragma unroll
            for (int r = 0; r < 4; ++r)
                C[(size_t)(row0 + r) * N + col] = acc[mi][ni][r];
        }
    }
}

// ---------------------------------------------------------------
// Fused conv(4)+bias+SiLU -> x_proj(+softplus), WxT (1024,36) f32.
// ---------------------------------------------------------------
__global__ __launch_bounds__(256) void conv_xproj_kernel(
    const float* __restrict__ xz,
    const float* __restrict__ conv_w,
    const float* __restrict__ conv_b,
    const float* __restrict__ WxT,    // (1024, 36)
    float* __restrict__ x_conv,
    float* __restrict__ P)            // (M,33)
{
    const int wave = threadIdx.x >> 6;
    const int lane = threadIdx.x & 63;
    const int m = blockIdx.x * 4 + wave;
    const int l = m & (SEQ - 1);

    float acc[33];
#pragma unroll
    for (int e = 0; e < 33; ++e) acc[e] = 0.f;

    for (int d = lane; d < DMODEL; d += 64) {
        float cacc = conv_b[d];
#pragma unroll
        for (int k = 0; k < 4; ++k) {
            const int ll = l + k - 3;
            if (ll >= 0)
                cacc += xz[(size_t)(m + k - 3) * 2048 + d] * conv_w[d * 4 + k];
        }
        const float xc = cacc / (1.f + __expf(-cacc));   // SiLU
        x_conv[(size_t)m * DMODEL + d] = xc;
        const f32x4* wr = (const f32x4*)(WxT + (size_t)d * 36);
#pragma unroll
        for (int q = 0; q < 8; ++q) {
            const f32x4 w = wr[q];
#pragma unroll
            for (int j = 0; j < 4; ++j) acc[q * 4 + j] += xc * w[j];
        }
        acc[32] += xc * WxT[(size_t)d * 36 + 32];
    }
#pragma unroll
    for (int e = 0; e < 33; ++e) {
        float v = acc[e];
#pragma unroll
        for (int off = 32; off; off >>= 1) v += __shfl_xor(v, off, 64);
        acc[e] = v;
    }
    if (lane == 0) {
        float* out = P + (size_t)m * 33;
        for (int e = 0; e < 32; ++e) out[e] = acc[e];
        const float x = acc[32];
        out[32] = (x > 20.f) ? x : log1pf(expf(x));      // softplus
    }
}

// ---------------------------------------------------------------
// Chunked parallel scan (3 phases).
// ---------------------------------------------------------------
__global__ __launch_bounds__(256) void scan_phase1(
    const float* __restrict__ P,
    const float* __restrict__ xc,
    const float* __restrict__ A_log,
    __bf16* __restrict__ hbuf,
    float* __restrict__ S)
{
    const int d = blockIdx.x * 256 + threadIdx.x;
    const int c = blockIdx.y;
    const int b = blockIdx.z;
    const int l0 = c * CLEN;

    __shared__ float buf[CLEN * 33];
    const float* src = P + (size_t)(b * SEQ + l0) * 33;
    for (int idx = threadIdx.x; idx < CLEN * 33; idx += 256)
        buf[idx] = src[idx];
    __syncthreads();

    if (threadIdx.x == 0 && blockIdx.x == 0) {
        float s = 0.f;
        for (int j = 0; j < CLEN; ++j) s += buf[j * 33 + 32];
        S[b * NCHUNK + c] = s;
    }

    float a[16];
#pragma unroll
    for (int n = 0; n < 16; ++n) a[n] = -__expf(A_log[d * 16 + n]);
    float h[16];
#pragma unroll
    for (int n = 0; n < 16; ++n) h[n] = 0.f;

    for (int j = 0; j < CLEN; ++j) {
        const int m = b * SEQ + l0 + j;
        const float xv = xc[(size_t)m * 1024 + d];
        const float* pp = &buf[j * 33];
        const float delta = pp[32];
        const float dx = delta * xv;
#pragma unroll
        for (int n = 0; n < 16; ++n)
            h[n] = __expf(delta * a[n]) * h[n] + dx * pp[n];
    }

    __bf16* hp = hbuf + ((size_t)(b * NCHUNK + c) * 1024 + d) * 16;
#pragma unroll
    for (int n = 0; n < 16; ++n) hp[n] = (__bf16)h[n];
}

__global__ __launch_bounds__(256) void scan_phase2(
    const float* __restrict__ A_log,
    const float* __restrict__ S,
    __bf16* __restrict__ hbuf)
{
    const int n = threadIdx.x & 15;
    const int d = blockIdx.x * 16 + (threadIdx.x >> 4);
    const int b = blockIdx.y;
    const float a = -__expf(A_log[d * 16 + n]);
    float h = 0.f;
    for (int c = 0; c < NCHUNK; ++c) {
        const size_t off = ((size_t)(b * NCHUNK + c) * 1024 + d) * 16 + n;
        const float he = (float)hbuf[off];
        hbuf[off] = (__bf16)h;
        h = __expf(a * S[b * NCHUNK + c]) * h + he;
    }
}

__global__ __launch_bounds__(256) void scan_phase3(
    const float* __restrict__ P,
    const float* __restrict__ xc,
    const float* __restrict__ xz,
    const float* __restrict__ A_log,
    const float* __restrict__ Dp,
    const __bf16* __restrict__ hbuf,
    __bf16* __restrict__ Y)
{
    const int d = blockIdx.x * 256 + threadIdx.x;
    const int c = blockIdx.y;
    const int b = blockIdx.z;
    const int l0 = c * CLEN;

    __shared__ float buf[CLEN * 33];
    const float* src = P + (size_t)(b * SEQ + l0) * 33;
    for (int idx = threadIdx.x; idx < CLEN * 33; idx += 256)
        buf[idx] = src[idx];
    __syncthreads();

    float a[16];
#pragma unroll
    for (int n = 0; n < 16; ++n) a[n] = -__expf(A_log[d * 16 + n]);
    const float Dv = Dp[d];

    const __bf16* hp = hbuf + ((size_t)(b * NCHUNK + c) * 1024 + d) * 16;
    float h[16];
#pragma unroll
    for (int n = 0; n < 16; ++n) h[n] = (float)hp[n];

    for (int j = 0; j < CLEN; ++j) {
        const int m = b * SEQ + l0 + j;
        const float xv = xc[(size_t)m * 1024 + d];
        const float zv = xz[(size_t)m * 2048 + 1024 + d];
        const float* pp = &buf[j * 33];
        const float delta = pp[32];
        const float dx = delta * xv;
        float y = 0.f;
#pragma unroll
        for (int n = 0; n < 16; ++n) {
            h[n] = __expf(delta * a[n]) * h[n] + dx * pp[n];
            y += h[n] * pp[16 + n];
        }
        y += Dv * xv;
        const float sz = zv / (1.f + __expf(-zv));
        Y[(size_t)m * 1024 + d] = (__bf16)(y * sz);
    }
}

// ---------------------------------------------------------------
extern "C" void kernel_launch(void* const* d_in, const int* in_sizes, int n_in,
                              void* d_out, int out_size, void* d_ws, size_t ws_size,
                              hipStream_t stream) {
    const float* x          = (const float*)d_in[0];
    const float* in_proj_w  = (const float*)d_in[1];
    const float* conv_w     = (const float*)d_in[2];
    const float* conv_b     = (const float*)d_in[3];
    const float* x_proj_w   = (const float*)d_in[4];
    const float* A_log      = (const float*)d_in[5];
    const float* D_param    = (const float*)d_in[6];
    const float* out_proj_w = (const float*)d_in[7];
    float* out = (float*)d_out;

    char* ws = (char*)d_ws;
    // Lifetimes:
    //  t0 cvt_all    writes x_hi, wi_hi, wi_lo, wo, wxT
    //  t1 gemm<true> reads x_hi, wi_* -> writes xz
    //  t2 conv_xproj reads xz, wxT -> writes xconv, params (over x_hi; dead)
    //  t3 scan       reads params, xconv, xz -> writes hbuf, y (over wxT; dead)
    //  t4 gemm<false> reads y, wo -> writes out
    float*  xz     = (float*)(ws);                 // [0, 64M)
    __bf16* x_hi   = (__bf16*)(ws + 67108864);     // [64M, 80M)
    __bf16* wi_hi  = (__bf16*)(ws + 100663296);    // [96M, 100M)
    __bf16* wi_lo  = (__bf16*)(ws + 104857600);    // [100M, 104M)
    float*  xconv  = (float*)(ws + 67108864);      // t2+: over x_hi
    float*  params = (float*)(ws + 100663296);     // t2+: over wi_hi head
    __bf16* hbuf   = (__bf16*)(ws + 101744640);    // t3: 4 MiB
    float*  Sbuf   = (float*)(ws + 105938944);     // t3: 512 B
    __bf16* y      = (__bf16*)(ws + 109051904);    // t3+: 16 MiB
    float*  wxT    = (float*)(ws + 109051904);     // t0-t2: head of y region
    __bf16* wo     = (__bf16*)(ws + 125829120);    // 2 MiB

    // 0) conversions + Wx transpose
    cvt_all<<<(NTOT + 255) / 256, 256, 0, stream>>>(
        x, in_proj_w, out_proj_w, x_proj_w,
        x_hi, wi_hi, wi_lo, wo, wxT);

    // 1) in_proj (M=8192,N=2048,K=1024): xz = x_bf16 @ (Wh+Wl)^T
    gemm_tile<true><<<dim3(2048 / 128, M_ROWS / 128), 256, 0, stream>>>(
        x_hi, wi_hi, wi_lo, xz, DMODEL, 2048);

    // 2) fused conv+SiLU+x_proj(+softplus)
    conv_xproj_kernel<<<M_ROWS / 4, 256, 0, stream>>>(
        xz, conv_w, conv_b, wxT, xconv, params);

    // 3) chunked parallel scan
    scan_phase1<<<dim3(DMODEL / 256, NCHUNK, BATCH), 256, 0, stream>>>(
        params, xconv, A_log, hbuf, Sbuf);
    scan_phase2<<<dim3(DMODEL / 16, BATCH), 256, 0, stream>>>(
        A_log, Sbuf, hbuf);
    scan_phase3<<<dim3(DMODEL / 256, NCHUNK, BATCH), 256, 0, stream>>>(
        params, xconv, xz, A_log, D_param, hbuf, y);

    // 4) out_proj (M=8192,N=1024,K=1024), plain bf16
    gemm_tile<false><<<dim3(1024 / 128, M_ROWS / 128), 256, 0, stream>>>(
        y, wo, nullptr, out, DMODEL, 1024);
}